// Round 4
// baseline (251.228 us; speedup 1.0000x reference)
//
#include <hip/hip_runtime.h>

// NPZD plankton ODE: B*WK = 106496 independent trajectories, 56 Euler steps.
//
// R10: R9 killed the occupancy theory (occ 11->33%, dur flat; its regression
// was 25 MB of VGPR spill traffic: VGPR=64, WRITE 13->38 MB). The surviving
// invariant across R2-R9 (63-76 us) is per-CU line service ~1.9-3.6 B/cy
// (vs m13's 10.2): every variant BURSTS VGPR-staged loads then drains to
// zero in-flight through compact+integrate, so the per-CU miss queue is
// empty most of the time (avg ~25 lines outstanding; x ~600cy latency
// reproduces 66 us).
// Fix: fire-and-forget DMA. global_load_lds (width 16, per-lane gather
// source, linear LDS dest) stages 7 chunks of 8 steps (6 f4/week/chunk),
// double-buffered: issue chunk c+1's 6 DMA instrs, counted-drain vmcnt(6)
// for chunk c, integrate. Zero staging VGPRs (no spill possible), zero
// compact VALU (integrate reads stride-3 from the raw chunk image), LDS
// 12.3 KB -> 13 blocks/CU, and each wave holds 6-12 DMA instrs in flight
// continuously -> the miss queue never drains.

typedef float f32x4 __attribute__((ext_vector_type(4)));

#define NPZD_B 2048
#define NPZD_WK 52
#define NPZD_HRS 8760
#define NPZD_WKH 26            // weeks per half-batch (one wave-block)
#define NPZD_CS 8              // steps per chunk (24 hours = 6 f4 per week)
#define NPZD_F4C 6             // f4 per week per chunk
#define NPZD_NI 156            // valid f4 per array per chunk = 26*6
#define NPZD_SLOTS 192         // padded to 3 DMA instrs x 64 lanes

typedef const __attribute__((address_space(1))) void* gas_t;
typedef __attribute__((address_space(3))) void* las_t;

// one chunk = 6 fire-and-forget DMA instrs (1 KB each, 64 lanes x 16 B).
// LDS dest is uniform base + lane*16 (linear); global src is per-lane.
#define NPZD_ISSUE(c, d) do { \
    __builtin_amdgcn_global_load_lds((gas_t)(const void*)(gf4 + kb0 + 6*(c)), (las_t)(void*)&lds[d][0][0],   16, 0, 0); \
    __builtin_amdgcn_global_load_lds((gas_t)(const void*)(gf4 + kb1 + 6*(c)), (las_t)(void*)&lds[d][0][64],  16, 0, 0); \
    __builtin_amdgcn_global_load_lds((gas_t)(const void*)(gf4 + kb2 + 6*(c)), (las_t)(void*)&lds[d][0][128], 16, 0, 0); \
    __builtin_amdgcn_global_load_lds((gas_t)(const void*)(gm4 + kb0 + 6*(c)), (las_t)(void*)&lds[d][1][0],   16, 0, 0); \
    __builtin_amdgcn_global_load_lds((gas_t)(const void*)(gm4 + kb1 + 6*(c)), (las_t)(void*)&lds[d][1][64],  16, 0, 0); \
    __builtin_amdgcn_global_load_lds((gas_t)(const void*)(gm4 + kb2 + 6*(c)), (las_t)(void*)&lds[d][1][128], 16, 0, 0); \
} while (0)

__global__ __launch_bounds__(64, 4) void npzd_kernel(
    const float* __restrict__ X_in,     // (B, WK, 5, 1)
    const float* __restrict__ gf,       // (B, HRS)
    const float* __restrict__ gm,       // (B, HRS)
    const float* __restrict__ params,   // (B, 10)
    const float* __restrict__ dt_ptr,   // scalar
    float* __restrict__ out)            // (B, WK, 4, 8)
{
    __shared__ __align__(16) f32x4 lds[2][2][NPZD_SLOTS];   // 12.3 KB

    const int bid  = blockIdx.x;
    const int b    = bid >> 1;
    const int hb   = bid & 1;           // half-batch: weeks [26*hb, 26*hb+26)
    const int lane = threadIdx.x;

    const f32x4* __restrict__ gf4 = (const f32x4*)(gf + (size_t)b * NPZD_HRS);
    const f32x4* __restrict__ gm4 = (const f32x4*)(gm + (size_t)b * NPZD_HRS);

    // slot i = 6*w + f  (w = week in half-batch, f = f4 within chunk-week)
    // global f4 index k = 42*(26*hb + w) + 6*c + f = 1092*hb + 42*w + f + 6c.
    // i/6 = (i*43691)>>18, exact for this range.
    int kb0, kb1, kb2;
    {
        const int i0 = lane;                                   // < 156
        const int i1 = 64 + lane;                              // < 156
        int i2 = 128 + lane; if (i2 >= NPZD_NI) i2 = NPZD_NI - 1;  // clamp: dup line, benign
        const int w0 = (i0 * 43691) >> 18, f0 = i0 - 6 * w0;
        const int w1 = (i1 * 43691) >> 18, f1 = i1 - 6 * w1;
        const int w2 = (i2 * 43691) >> 18, f2 = i2 - 6 * w2;
        kb0 = 1092 * hb + 42 * w0 + f0;
        kb1 = 1092 * hb + 42 * w1 + f1;
        kb2 = 1092 * hb + 42 * w2 + f2;
    }

    NPZD_ISSUE(0, 0);   // chunk 0 in flight immediately

    // hoisted scalars overlap the first DMA
    const float dt = dt_ptr[0];   // 0.125
    const int wl = (lane < NPZD_WKH) ? lane : (NPZD_WKH - 1);
    const int wg = NPZD_WKH * hb + wl;                          // global week
    const float* xb = X_in + ((size_t)b * NPZD_WK + wg) * 5;
    float N = xb[1], P = xb[2], Z = xb[3], D = xb[4];

    const float* pp = params + (size_t)b * 10;   // block-uniform -> s_load
    const float chi   = pp[0];
    const float rho2  = pp[1] * 2.0f;
    const float gam1  = pp[2] * 0.1f;
    const float lam05 = pp[3] * 0.05f;
    const float eps1  = pp[4] * 0.1f;
    const float alp3  = pp[5] * 0.3f;
    const float bet6  = pp[6] * 0.6f;
    const float eta15 = pp[7] * 0.15f;
    const float phi4  = pp[8] * 0.4f;
    const float zet1  = pp[9] * 0.1f;
    const float rem   = 1.0f - alp3 - bet6;

    float oN[8], oP[8], oZ[8], oD[8];
    oN[0] = N; oP[0] = P; oZ[0] = Z; oD[0] = D;

    #pragma unroll
    for (int c = 0; c < 7; ++c) {
        const int d = c & 1;
        // issue next chunk BEFORE consuming current (T3/T4 pattern):
        // buf[d^1] was last read in chunk c-1 (program order, lgkm drained
        // by use) -> safe to overwrite.
        if (c < 6) {
            NPZD_ISSUE(c + 1, d ^ 1);
            asm volatile("s_waitcnt vmcnt(6)" ::: "memory");   // chunk c landed
        } else {
            asm volatile("s_waitcnt vmcnt(0)" ::: "memory");
        }
        __builtin_amdgcn_sched_barrier(0);

        // integrate 8 steps from the raw chunk image: week wl's 24 words
        // start at word 24*wl; step s uses word 3s (hour%3 compaction done
        // by the read pattern itself, no compact pass).
        if (lane < NPZD_WKH) {
            const float* lf = (const float*)&lds[d][0][0] + 24 * wl;
            const float* lm = (const float*)&lds[d][1][0] + 24 * wl;
            #pragma unroll
            for (int s = 0; s < NPZD_CS; ++s) {
                const float ft = lf[3 * s];
                const float mt = lm[3 * s];
                const float Pc = fmaxf(0.01f, P);
                const float Zc = fmaxf(0.01f, Z);
                const float gN = N * __builtin_amdgcn_rcpf(chi + N);
                const float zg = rho2 * (1.0f - __expf(-lam05 * Pc)) * Zc;
                const float up = gN * ft * Pc;
                const float Nn = N + dt * (-up + alp3 * zg + eps1 * P + gam1 * Z + phi4 * D + mt * (8.0f - N));
                const float Pn = P + dt * (up - zg - eps1 * P - eta15 * P - mt * P);
                const float Zn = Z + dt * (bet6 * zg - gam1 * Z - mt * Z);
                const float Dn = D + dt * (eta15 * P + rem * zg - phi4 * D - zet1 * D - mt * D);
                N = Nn; P = Pn; Z = Zn; D = Dn;
            }
            // checkpoint after steps 7,15,...,55 = end of every chunk
            oN[c + 1] = N; oP[c + 1] = P; oZ[c + 1] = Z; oD[c + 1] = D;
        }
    }

    // ---- output: (b, wg, state, 8) -> 32 contiguous floats/trajectory ----
    if (lane >= NPZD_WKH) return;
    f32x4* o4 = (f32x4*)(out + ((size_t)b * NPZD_WK + wg) * 32);
    o4[0] = (f32x4){oN[0], oN[1], oN[2], oN[3]};
    o4[1] = (f32x4){oN[4], oN[5], oN[6], oN[7]};
    o4[2] = (f32x4){oP[0], oP[1], oP[2], oP[3]};
    o4[3] = (f32x4){oP[4], oP[5], oP[6], oP[7]};
    o4[4] = (f32x4){oZ[0], oZ[1], oZ[2], oZ[3]};
    o4[5] = (f32x4){oZ[4], oZ[5], oZ[6], oZ[7]};
    o4[6] = (f32x4){oD[0], oD[1], oD[2], oD[3]};
    o4[7] = (f32x4){oD[4], oD[5], oD[6], oD[7]};
}

extern "C" void kernel_launch(void* const* d_in, const int* in_sizes, int n_in,
                              void* d_out, int out_size, void* d_ws, size_t ws_size,
                              hipStream_t stream) {
    const float* X_in   = (const float*)d_in[0];
    const float* gf     = (const float*)d_in[1];
    const float* gm     = (const float*)d_in[2];
    const float* params = (const float*)d_in[3];
    const float* dt_ptr = (const float*)d_in[4];
    float* out = (float*)d_out;

    npzd_kernel<<<NPZD_B * 2, 64, 0, stream>>>(X_in, gf, gm, params, dt_ptr, out);
}

// Round 5
// 192.884 us; speedup vs baseline: 1.3025x; 1.3025x over previous
//
#include <hip/hip_runtime.h>

// NPZD plankton ODE: B*WK = 106496 independent trajectories, 56 Euler steps.
//
// R11: R10's scattered-source global_load_lds shattered each DMA into ~26
// segments (FETCH 180 MB, spurious WRITE 182 MB, 140 us) - dead end.
// The durable R2-R9 invariant: monolithic kernels time-multiplex streaming
// with a serial integrate, the in-flight window drains to zero most of each
// wave's lifetime, and the read path runs at 2-3.6 B/cy/CU.
// Fix: split into two dispatches through d_ws.
//  K1 npzd_stage: pure streaming. One block/batch, R6's PROVEN stage+compact
//    LDS image (identical math), then coalesced writes of the compacted
//    series to ws as fc[b][g][w] (f4 = steps 4g..4g+3 of week w; source is
//    one aligned b128 LDS read at 60w+4g). No serial tail; 24 waves/CU keep
//    the miss queue continuously fed.
//  K2 npzd_integrate: pure compute. 4 waves/block, wave=batch, lane=week;
//    per 4 steps two 832B coalesced f4 loads from the L3-hot intermediate.
//    No LDS, no barriers. ~8 waves/CU, serial-chain wall ~2-4 us.
// Fallback: ws too small -> known-good R8 monolith (66 us).

typedef float f32x4 __attribute__((ext_vector_type(4)));

#define NPZD_B 2048
#define NPZD_WK 52
#define NPZD_HRS 8760
#define NPZD_NF4 2190          // 8760/4 float4 per row
#define NPZD_WSTRIDE 60        // padded words per week (16B-aligned)
#define NPZD_LDSW (NPZD_WK * NPZD_WSTRIDE + 16)   // 3136; p max 3127
#define NPZD_OPB 728           // compacted f4 per array per batch = 52*14

// ---------------------------------------------------------------------------
// K1: stage + compact (R6-proven) + transposed coalesced write to workspace
// ---------------------------------------------------------------------------
__global__ __launch_bounds__(256) void npzd_stage(
    const float* __restrict__ gf,       // (B, HRS)
    const float* __restrict__ gm,       // (B, HRS)
    f32x4* __restrict__ fc,             // (B, 14, 52) f4
    f32x4* __restrict__ mc)             // (B, 14, 52) f4
{
    __shared__ __align__(16) float lds_f[NPZD_LDSW];
    __shared__ __align__(16) float lds_m[NPZD_LDSW];

    const int b   = blockIdx.x;
    const int tid = threadIdx.x;

    const f32x4* __restrict__ gf4 = (const f32x4*)(gf + (size_t)b * NPZD_HRS);
    const f32x4* __restrict__ gm4 = (const f32x4*)(gm + (size_t)b * NPZD_HRS);

    // ---- stage the whole row, fully coalesced, all in flight ----
    f32x4 fv[9], mv[9];
    int kk[9];
    #pragma unroll
    for (int i = 0; i < 9; ++i) {
        int k = i * 256 + tid;
        if (k >= NPZD_NF4) k = NPZD_NF4 - 1;   // clamp: dup load+dup write, benign
        kk[i] = k;
        fv[i] = gf4[k];
        mv[i] = gm4[k];
    }

    // ---- compact every-3rd word into LDS (R6-verified math) ----
    // float4 k covers h = 4k..4k+3. h%3==0 at e0=(3-k%3)%3 (and e0+3 if
    // k%3==0). j = h/3; dest p = j + 4*(j/56); (j*9363)>>19 == j/56 for
    // j <= 2919.
    #pragma unroll
    for (int i = 0; i < 9; ++i) {
        const int k = kk[i];
        const float fe[4] = {fv[i].x, fv[i].y, fv[i].z, fv[i].w};
        const float me[4] = {mv[i].x, mv[i].y, mv[i].z, mv[i].w};
        const int rm = k % 3;
        const int e0 = (rm == 0) ? 0 : (3 - rm);
        const int j0 = (4 * k + e0) / 3;
        const int p0 = j0 + 4 * ((j0 * 9363) >> 19);
        lds_f[p0] = fe[e0];
        lds_m[p0] = me[e0];
        if (rm == 0) {               // second multiple of 3 in this float4 (e=3)
            const int j1 = j0 + 1;
            const int p1 = j1 + 4 * ((j1 * 9363) >> 19);
            lds_f[p1] = fe[3];
            lds_m[p1] = me[3];
        }
    }
    __syncthreads();

    // ---- transposed write-out: o = 52*g + w  ->  fc[b*728 + o] ----
    // source f4 = steps 4g..4g+3 of week w = lds[60w+4g..+3] (16B-aligned).
    // o/52 = (o*5042)>>18, exact for o < 728 (edges 51,52,675,676,727 checked).
    #pragma unroll
    for (int i = 0; i < 3; ++i) {
        const int o = tid + 256 * i;
        if (o < NPZD_OPB) {
            const int g = (o * 5042) >> 18;
            const int w = o - 52 * g;
            const int src = 60 * w + 4 * g;
            fc[(size_t)b * NPZD_OPB + o] = *(const f32x4*)(lds_f + src);
            mc[(size_t)b * NPZD_OPB + o] = *(const f32x4*)(lds_m + src);
        }
    }
}

// ---------------------------------------------------------------------------
// K2: pure integrate. wave = batch, lane = week, coalesced f4 reads from ws.
// ---------------------------------------------------------------------------
__global__ __launch_bounds__(256) void npzd_integrate(
    const float* __restrict__ X_in,     // (B, WK, 5, 1)
    const f32x4* __restrict__ fc,       // (B, 14, 52) f4
    const f32x4* __restrict__ mc,
    const float* __restrict__ params,   // (B, 10)
    const float* __restrict__ dt_ptr,
    float* __restrict__ out)            // (B, WK, 4, 8)
{
    const int wave = threadIdx.x >> 6;
    const int lane = threadIdx.x & 63;
    const int b    = blockIdx.x * 4 + wave;
    const int wl   = (lane < NPZD_WK) ? lane : (NPZD_WK - 1);   // dup, masked at store

    const float dt = dt_ptr[0];   // 0.125
    const float* xb = X_in + ((size_t)b * NPZD_WK + wl) * 5;
    float N = xb[1], P = xb[2], Z = xb[3], D = xb[4];

    const float* pp = params + (size_t)b * 10;   // wave-uniform
    const float chi   = pp[0];
    const float rho2  = pp[1] * 2.0f;
    const float gam1  = pp[2] * 0.1f;
    const float lam05 = pp[3] * 0.05f;
    const float eps1  = pp[4] * 0.1f;
    const float alp3  = pp[5] * 0.3f;
    const float bet6  = pp[6] * 0.6f;
    const float eta15 = pp[7] * 0.15f;
    const float phi4  = pp[8] * 0.4f;
    const float zet1  = pp[9] * 0.1f;
    const float rem   = 1.0f - alp3 - bet6;

    float oN[8], oP[8], oZ[8], oD[8];
    oN[0] = N; oP[0] = P; oZ[0] = Z; oD[0] = D;

    const size_t base = (size_t)b * NPZD_OPB + wl;

    #pragma unroll
    for (int g = 0; g < 14; ++g) {
        // lanes 0..51 read 52 consecutive f4 (832B) -> fully coalesced
        const f32x4 f4 = fc[base + 52 * g];
        const f32x4 m4 = mc[base + 52 * g];
        const float fs[4] = {f4.x, f4.y, f4.z, f4.w};
        const float ms[4] = {m4.x, m4.y, m4.z, m4.w};
        #pragma unroll
        for (int q = 0; q < 4; ++q) {
            const float ft = fs[q], mt = ms[q];
            const float Pc = fmaxf(0.01f, P);
            const float Zc = fmaxf(0.01f, Z);
            const float gN = N * __builtin_amdgcn_rcpf(chi + N);
            const float zg = rho2 * (1.0f - __expf(-lam05 * Pc)) * Zc;
            const float up = gN * ft * Pc;
            const float Nn = N + dt * (-up + alp3 * zg + eps1 * P + gam1 * Z + phi4 * D + mt * (8.0f - N));
            const float Pn = P + dt * (up - zg - eps1 * P - eta15 * P - mt * P);
            const float Zn = Z + dt * (bet6 * zg - gam1 * Z - mt * Z);
            const float Dn = D + dt * (eta15 * P + rem * zg - phi4 * D - zet1 * D - mt * D);
            N = Nn; P = Pn; Z = Zn; D = Dn;
        }
        if (g & 1) {   // after steps 7,15,...,55
            const int c = (g >> 1) + 1;
            oN[c] = N; oP[c] = P; oZ[c] = Z; oD[c] = D;
        }
    }

    if (lane >= NPZD_WK) return;
    f32x4* o4 = (f32x4*)(out + ((size_t)b * NPZD_WK + wl) * 32);
    o4[0] = (f32x4){oN[0], oN[1], oN[2], oN[3]};
    o4[1] = (f32x4){oN[4], oN[5], oN[6], oN[7]};
    o4[2] = (f32x4){oP[0], oP[1], oP[2], oP[3]};
    o4[3] = (f32x4){oP[4], oP[5], oP[6], oP[7]};
    o4[4] = (f32x4){oZ[0], oZ[1], oZ[2], oZ[3]};
    o4[5] = (f32x4){oZ[4], oZ[5], oZ[6], oZ[7]};
    o4[6] = (f32x4){oD[0], oD[1], oD[2], oD[3]};
    o4[7] = (f32x4){oD[4], oD[5], oD[6], oD[7]};
}

// ---------------------------------------------------------------------------
// Fallback monolith (R8, known-good 66 us) if workspace is too small.
// ---------------------------------------------------------------------------
__global__ __launch_bounds__(64, 4) void npzd_mono(
    const float* __restrict__ X_in, const float* __restrict__ gf,
    const float* __restrict__ gm, const float* __restrict__ params,
    const float* __restrict__ dt_ptr, float* __restrict__ out)
{
    __shared__ __align__(16) float lds_f[NPZD_LDSW];
    __shared__ __align__(16) float lds_m[NPZD_LDSW];

    const int b    = blockIdx.x;
    const int lane = threadIdx.x;

    const float dt = dt_ptr[0];
    const int wc = (lane < NPZD_WK) ? lane : (NPZD_WK - 1);
    const float* xb = X_in + ((size_t)b * NPZD_WK + wc) * 5;
    const float x1 = xb[1], x2 = xb[2], x3 = xb[3], x4 = xb[4];

    const float* pp = params + (size_t)b * 10;
    const float chi   = pp[0];
    const float rho2  = pp[1] * 2.0f;
    const float gam1  = pp[2] * 0.1f;
    const float lam05 = pp[3] * 0.05f;
    const float eps1  = pp[4] * 0.1f;
    const float alp3  = pp[5] * 0.3f;
    const float bet6  = pp[6] * 0.6f;
    const float eta15 = pp[7] * 0.15f;
    const float phi4  = pp[8] * 0.4f;
    const float zet1  = pp[9] * 0.1f;
    const float rem   = 1.0f - alp3 - bet6;

    const f32x4* __restrict__ gf4 = (const f32x4*)(gf + (size_t)b * NPZD_HRS);
    const f32x4* __restrict__ gm4 = (const f32x4*)(gm + (size_t)b * NPZD_HRS);

    #pragma unroll
    for (int pass = 0; pass < 4; ++pass) {
        f32x4 fv[9], mv[9];
        int kk[9];
        #pragma unroll
        for (int c = 0; c < 9; ++c) {
            int k = (pass * 9 + c) * 64 + lane;
            if (k >= NPZD_NF4) k = NPZD_NF4 - 1;
            kk[c] = k;
            fv[c] = gf4[k];
            mv[c] = gm4[k];
        }
        #pragma unroll
        for (int c = 0; c < 9; ++c) {
            const int k = kk[c];
            const float fe[4] = {fv[c].x, fv[c].y, fv[c].z, fv[c].w};
            const float me[4] = {mv[c].x, mv[c].y, mv[c].z, mv[c].w};
            const int rm = k % 3;
            const int e0 = (rm == 0) ? 0 : (3 - rm);
            const int j0 = (4 * k + e0) / 3;
            const int p0 = j0 + 4 * ((j0 * 9363) >> 19);
            lds_f[p0] = fe[e0];
            lds_m[p0] = me[e0];
            if (rm == 0) {
                const int j1 = j0 + 1;
                const int p1 = j1 + 4 * ((j1 * 9363) >> 19);
                lds_f[p1] = fe[3];
                lds_m[p1] = me[3];
            }
        }
    }
    __syncthreads();

    if (lane >= NPZD_WK) return;
    const int w = lane;
    float N = x1, P = x2, Z = x3, D = x4;
    float oN[8], oP[8], oZ[8], oD[8];
    oN[0] = N; oP[0] = P; oZ[0] = Z; oD[0] = D;
    const float* lf = lds_f + w * NPZD_WSTRIDE;
    const float* lm = lds_m + w * NPZD_WSTRIDE;
    #pragma unroll
    for (int g = 0; g < 14; ++g) {
        const f32x4 f4 = *(const f32x4*)(lf + 4 * g);
        const f32x4 m4 = *(const f32x4*)(lm + 4 * g);
        const float fs[4] = {f4.x, f4.y, f4.z, f4.w};
        const float ms[4] = {m4.x, m4.y, m4.z, m4.w};
        #pragma unroll
        for (int q = 0; q < 4; ++q) {
            const float ft = fs[q], mt = ms[q];
            const float Pc = fmaxf(0.01f, P);
            const float Zc = fmaxf(0.01f, Z);
            const float gN = N * __builtin_amdgcn_rcpf(chi + N);
            const float zg = rho2 * (1.0f - __expf(-lam05 * Pc)) * Zc;
            const float up = gN * ft * Pc;
            const float Nn = N + dt * (-up + alp3 * zg + eps1 * P + gam1 * Z + phi4 * D + mt * (8.0f - N));
            const float Pn = P + dt * (up - zg - eps1 * P - eta15 * P - mt * P);
            const float Zn = Z + dt * (bet6 * zg - gam1 * Z - mt * Z);
            const float Dn = D + dt * (eta15 * P + rem * zg - phi4 * D - zet1 * D - mt * D);
            N = Nn; P = Pn; Z = Zn; D = Dn;
        }
        if (g & 1) {
            const int c = (g >> 1) + 1;
            oN[c] = N; oP[c] = P; oZ[c] = Z; oD[c] = D;
        }
    }
    f32x4* o4 = (f32x4*)(out + ((size_t)b * NPZD_WK + w) * 32);
    o4[0] = (f32x4){oN[0], oN[1], oN[2], oN[3]};
    o4[1] = (f32x4){oN[4], oN[5], oN[6], oN[7]};
    o4[2] = (f32x4){oP[0], oP[1], oP[2], oP[3]};
    o4[3] = (f32x4){oP[4], oP[5], oP[6], oP[7]};
    o4[4] = (f32x4){oZ[0], oZ[1], oZ[2], oZ[3]};
    o4[5] = (f32x4){oZ[4], oZ[5], oZ[6], oZ[7]};
    o4[6] = (f32x4){oD[0], oD[1], oD[2], oD[3]};
    o4[7] = (f32x4){oD[4], oD[5], oD[6], oD[7]};
}

extern "C" void kernel_launch(void* const* d_in, const int* in_sizes, int n_in,
                              void* d_out, int out_size, void* d_ws, size_t ws_size,
                              hipStream_t stream) {
    const float* X_in   = (const float*)d_in[0];
    const float* gf     = (const float*)d_in[1];
    const float* gm     = (const float*)d_in[2];
    const float* params = (const float*)d_in[3];
    const float* dt_ptr = (const float*)d_in[4];
    float* out = (float*)d_out;

    const size_t need = (size_t)2 * NPZD_B * NPZD_OPB * sizeof(f32x4);  // 47.7 MB
    if (ws_size >= need && d_ws != nullptr) {
        f32x4* fc = (f32x4*)d_ws;
        f32x4* mc = fc + (size_t)NPZD_B * NPZD_OPB;
        npzd_stage<<<NPZD_B, 256, 0, stream>>>(gf, gm, fc, mc);
        npzd_integrate<<<NPZD_B / 4, 256, 0, stream>>>(X_in, fc, mc, params, dt_ptr, out);
    } else {
        npzd_mono<<<NPZD_B, 64, 0, stream>>>(X_in, gf, gm, params, dt_ptr, out);
    }
}